// Round 6
// baseline (27.313 us; speedup 1.0000x reference)
//
#include <hip/hip_runtime.h>

#define BATCH   16384
#define DIM     1024
#define NLAYERS 4
#define NF4     (DIM / 4)     // 256 float4 per row
#define THREADS 256           // 4 waves per block
#define NBLOCKS 2048          // 8192 waves x 2 rows = 16384 rows

typedef float floatx4 __attribute__((ext_vector_type(4)));

// x_L = alpha * x0 + bsum;  alpha = 1 + sum_l s_l,
// s_l = alpha_l * (x0 . W[l]) + c_l,  c_l = (sum_{k<l} b[k]) . W[l].
// Row-0 x-loads are issued FIRST so the HBM stream starts before the
// prologue's dependent W/b work; row-1 loads issue right after the barrier
// and their latency hides under row-0's dot+reduce+store.
__global__ __launch_bounds__(THREADS) void crossnet_kernel(
    const float* __restrict__ x0,
    const float* __restrict__ W,
    const float* __restrict__ b,
    float* __restrict__ out)
{
    __shared__ float4 lW[NLAYERS * NF4];   // 16 KB staged W
    __shared__ float4 lBsum[NF4];          //  4 KB
    __shared__ float  redc[3][4];

    const int tid  = threadIdx.x;
    const int lane = tid & 63;
    const int wv   = tid >> 6;

    const int gw = blockIdx.x * (THREADS / 64) + wv;   // 0..8191
    const size_t r0 = (size_t)(2 * gw);
    const size_t r1 = r0 + 1;
    const float4* xa = reinterpret_cast<const float4*>(x0) + r0 * NF4;
    const float4* xb = reinterpret_cast<const float4*>(x0) + r1 * NF4;

    // ---- issue row-0 stream loads BEFORE any prologue work ----
    float4 A[4];
#pragma unroll
    for (int j = 0; j < 4; ++j) A[j] = xa[j * 64 + lane];

    const float4* Wv = reinterpret_cast<const float4*>(W);
    const float4* bv = reinterpret_cast<const float4*>(b);

    // ---- prologue: stage W, build bsum and c_l constants ----
#pragma unroll
    for (int i = 0; i < NLAYERS * NF4 / THREADS; ++i)
        lW[tid + i * THREADS] = Wv[tid + i * THREADS];

    float4 b0 = bv[0 * NF4 + tid];
    float4 b1 = bv[1 * NF4 + tid];
    float4 b2 = bv[2 * NF4 + tid];
    float4 b3 = bv[3 * NF4 + tid];
    float4 w1 = Wv[1 * NF4 + tid];
    float4 w2 = Wv[2 * NF4 + tid];
    float4 w3 = Wv[3 * NF4 + tid];

    float4 pre = b0;
    float c1 = pre.x * w1.x + pre.y * w1.y + pre.z * w1.z + pre.w * w1.w;
    pre.x += b1.x; pre.y += b1.y; pre.z += b1.z; pre.w += b1.w;
    float c2 = pre.x * w2.x + pre.y * w2.y + pre.z * w2.z + pre.w * w2.w;
    pre.x += b2.x; pre.y += b2.y; pre.z += b2.z; pre.w += b2.w;
    float c3 = pre.x * w3.x + pre.y * w3.y + pre.z * w3.z + pre.w * w3.w;
    pre.x += b3.x; pre.y += b3.y; pre.z += b3.z; pre.w += b3.w;
    lBsum[tid] = pre;

#pragma unroll
    for (int off = 32; off; off >>= 1) {
        c1 += __shfl_xor(c1, off, 64);
        c2 += __shfl_xor(c2, off, 64);
        c3 += __shfl_xor(c3, off, 64);
    }
    if (lane == 0) { redc[0][wv] = c1; redc[1][wv] = c2; redc[2][wv] = c3; }
    __syncthreads();
    const float cp1 = redc[0][0] + redc[0][1] + redc[0][2] + redc[0][3];
    const float cp2 = redc[1][0] + redc[1][1] + redc[1][2] + redc[1][3];
    const float cp3 = redc[2][0] + redc[2][1] + redc[2][2] + redc[2][3];

    // ---- issue row-1 stream loads now; latency hides under row-0 work ----
    float4 B[4];
#pragma unroll
    for (int j = 0; j < 4; ++j) B[j] = xb[j * 64 + lane];

    float4 bs[4];
#pragma unroll
    for (int j = 0; j < 4; ++j) bs[j] = lBsum[j * 64 + lane];

    // ---- row 0: dot, reduce, recurrence, store ----
    float da[NLAYERS] = {0.f, 0.f, 0.f, 0.f};
#pragma unroll
    for (int j = 0; j < 4; ++j) {
        const int fi = j * 64 + lane;
#pragma unroll
        for (int l = 0; l < NLAYERS; ++l) {
            float4 wl = lW[l * NF4 + fi];
            da[l] += A[j].x * wl.x + A[j].y * wl.y + A[j].z * wl.z + A[j].w * wl.w;
        }
    }
#pragma unroll
    for (int off = 32; off; off >>= 1)
#pragma unroll
        for (int l = 0; l < NLAYERS; ++l)
            da[l] += __shfl_xor(da[l], off, 64);

    float alA = 1.0f;
    { float s = alA * da[0];            alA += s;
      s = fmaf(alA, da[1], cp1);        alA += s;
      s = fmaf(alA, da[2], cp2);        alA += s;
      s = fmaf(alA, da[3], cp3);        alA += s; }

    floatx4* oa = reinterpret_cast<floatx4*>(out) + r0 * NF4;
#pragma unroll
    for (int j = 0; j < 4; ++j) {
        floatx4 o;
        o.x = fmaf(alA, A[j].x, bs[j].x);
        o.y = fmaf(alA, A[j].y, bs[j].y);
        o.z = fmaf(alA, A[j].z, bs[j].z);
        o.w = fmaf(alA, A[j].w, bs[j].w);
        __builtin_nontemporal_store(o, &oa[j * 64 + lane]);
    }

    // ---- row 1: dot, reduce, recurrence, store ----
    float db[NLAYERS] = {0.f, 0.f, 0.f, 0.f};
#pragma unroll
    for (int j = 0; j < 4; ++j) {
        const int fi = j * 64 + lane;
#pragma unroll
        for (int l = 0; l < NLAYERS; ++l) {
            float4 wl = lW[l * NF4 + fi];
            db[l] += B[j].x * wl.x + B[j].y * wl.y + B[j].z * wl.z + B[j].w * wl.w;
        }
    }
#pragma unroll
    for (int off = 32; off; off >>= 1)
#pragma unroll
        for (int l = 0; l < NLAYERS; ++l)
            db[l] += __shfl_xor(db[l], off, 64);

    float alB = 1.0f;
    { float s = alB * db[0];            alB += s;
      s = fmaf(alB, db[1], cp1);        alB += s;
      s = fmaf(alB, db[2], cp2);        alB += s;
      s = fmaf(alB, db[3], cp3);        alB += s; }

    floatx4* ob = reinterpret_cast<floatx4*>(out) + r1 * NF4;
#pragma unroll
    for (int j = 0; j < 4; ++j) {
        floatx4 o;
        o.x = fmaf(alB, B[j].x, bs[j].x);
        o.y = fmaf(alB, B[j].y, bs[j].y);
        o.z = fmaf(alB, B[j].z, bs[j].z);
        o.w = fmaf(alB, B[j].w, bs[j].w);
        __builtin_nontemporal_store(o, &ob[j * 64 + lane]);
    }
}

extern "C" void kernel_launch(void* const* d_in, const int* in_sizes, int n_in,
                              void* d_out, int out_size, void* d_ws, size_t ws_size,
                              hipStream_t stream) {
    const float* x0 = (const float*)d_in[0];
    const float* W  = (const float*)d_in[1];
    const float* b  = (const float*)d_in[2];
    float* out      = (float*)d_out;

    crossnet_kernel<<<NBLOCKS, THREADS, 0, stream>>>(x0, W, b, out);
}

// Round 7
// 25.926 us; speedup vs baseline: 1.0535x; 1.0535x over previous
//
#include <hip/hip_runtime.h>

#define BATCH   16384
#define DIM     1024
#define NLAYERS 4
#define NF4     (DIM / 4)     // 256 float4 per row
#define THREADS 256           // 4 waves per block
#define NBLOCKS 2048          // 8192 waves x 2 rows = 16384 rows

typedef float floatx4 __attribute__((ext_vector_type(4)));

// x_L = alpha * x0 + bsum;  alpha = 1 + sum_l s_l,
// s_l = alpha_l * (x0 . W[l]) + c_l,  c_l = (sum_{k<l} b[k]) . W[l].
// LDS is EXACTLY 20480 B = 160KB/8 -> 8 blocks/CU -> all 2048 blocks
// co-resident in ONE generation (no serial tail). The cross-wave reduce
// scratch is overlaid on lBsum (barrier-separated) to avoid +48B tipping
// the allocation to 20992 B (7 blocks/CU + 12.5% tail, as in R5).
__global__ __launch_bounds__(THREADS) void crossnet_kernel(
    const float* __restrict__ x0,
    const float* __restrict__ W,
    const float* __restrict__ b,
    float* __restrict__ out)
{
    __shared__ float4 lW[NLAYERS * NF4];   // 16384 B staged W
    __shared__ float4 lBsum[NF4];          //  4096 B (first 12 floats double as scratch)

    const int tid  = threadIdx.x;
    const int lane = tid & 63;
    const int wv   = tid >> 6;

    const float4* Wv = reinterpret_cast<const float4*>(W);
    const float4* bv = reinterpret_cast<const float4*>(b);

    // ---- prologue: stage W, build bsum and c_l constants ----
#pragma unroll
    for (int i = 0; i < NLAYERS * NF4 / THREADS; ++i)
        lW[tid + i * THREADS] = Wv[tid + i * THREADS];

    float4 b0 = bv[0 * NF4 + tid];
    float4 b1 = bv[1 * NF4 + tid];
    float4 b2 = bv[2 * NF4 + tid];
    float4 b3 = bv[3 * NF4 + tid];
    float4 w1 = Wv[1 * NF4 + tid];
    float4 w2 = Wv[2 * NF4 + tid];
    float4 w3 = Wv[3 * NF4 + tid];

    float4 pre = b0;
    float c1 = pre.x * w1.x + pre.y * w1.y + pre.z * w1.z + pre.w * w1.w;
    pre.x += b1.x; pre.y += b1.y; pre.z += b1.z; pre.w += b1.w;
    float c2 = pre.x * w2.x + pre.y * w2.y + pre.z * w2.z + pre.w * w2.w;
    pre.x += b2.x; pre.y += b2.y; pre.z += b2.z; pre.w += b2.w;
    float c3 = pre.x * w3.x + pre.y * w3.y + pre.z * w3.z + pre.w * w3.w;
    pre.x += b3.x; pre.y += b3.y; pre.z += b3.z; pre.w += b3.w;

#pragma unroll
    for (int off = 32; off; off >>= 1) {
        c1 += __shfl_xor(c1, off, 64);
        c2 += __shfl_xor(c2, off, 64);
        c3 += __shfl_xor(c3, off, 64);
    }
    float* scratch = reinterpret_cast<float*>(lBsum);   // overlay, pre-lBsum
    if (lane == 0) { scratch[wv] = c1; scratch[4 + wv] = c2; scratch[8 + wv] = c3; }
    __syncthreads();
    const float cp1 = scratch[0] + scratch[1] + scratch[2]  + scratch[3];
    const float cp2 = scratch[4] + scratch[5] + scratch[6]  + scratch[7];
    const float cp3 = scratch[8] + scratch[9] + scratch[10] + scratch[11];
    __syncthreads();                    // scratch reads done before overwrite
    lBsum[tid] = pre;
    __syncthreads();

    float4 bs[4];
#pragma unroll
    for (int j = 0; j < 4; ++j) bs[j] = lBsum[j * 64 + lane];

    // ---- two rows per wave, interleaved (R5 structure) ----
    const int gw = blockIdx.x * (THREADS / 64) + wv;   // 0..8191
    const size_t r0 = (size_t)(2 * gw);
    const size_t r1 = r0 + 1;

    const float4* xa = reinterpret_cast<const float4*>(x0) + r0 * NF4;
    const float4* xb = reinterpret_cast<const float4*>(x0) + r1 * NF4;

    float4 A[4], B[4];
#pragma unroll
    for (int j = 0; j < 4; ++j) A[j] = xa[j * 64 + lane];
#pragma unroll
    for (int j = 0; j < 4; ++j) B[j] = xb[j * 64 + lane];

    float da[NLAYERS] = {0.f, 0.f, 0.f, 0.f};
    float db[NLAYERS] = {0.f, 0.f, 0.f, 0.f};
#pragma unroll
    for (int j = 0; j < 4; ++j) {
        const int fi = j * 64 + lane;
#pragma unroll
        for (int l = 0; l < NLAYERS; ++l) {
            float4 wl = lW[l * NF4 + fi];
            da[l] += A[j].x * wl.x + A[j].y * wl.y + A[j].z * wl.z + A[j].w * wl.w;
            db[l] += B[j].x * wl.x + B[j].y * wl.y + B[j].z * wl.z + B[j].w * wl.w;
        }
    }

#pragma unroll
    for (int off = 32; off; off >>= 1) {
#pragma unroll
        for (int l = 0; l < NLAYERS; ++l) {
            da[l] += __shfl_xor(da[l], off, 64);
            db[l] += __shfl_xor(db[l], off, 64);
        }
    }

    float alA = 1.0f, alB = 1.0f;
    { float s = alA * da[0];            alA += s;
      s = fmaf(alA, da[1], cp1);        alA += s;
      s = fmaf(alA, da[2], cp2);        alA += s;
      s = fmaf(alA, da[3], cp3);        alA += s; }
    { float s = alB * db[0];            alB += s;
      s = fmaf(alB, db[1], cp1);        alB += s;
      s = fmaf(alB, db[2], cp2);        alB += s;
      s = fmaf(alB, db[3], cp3);        alB += s; }

    floatx4* oa = reinterpret_cast<floatx4*>(out) + r0 * NF4;
    floatx4* ob = reinterpret_cast<floatx4*>(out) + r1 * NF4;
#pragma unroll
    for (int j = 0; j < 4; ++j) {
        floatx4 o;
        o.x = fmaf(alA, A[j].x, bs[j].x);
        o.y = fmaf(alA, A[j].y, bs[j].y);
        o.z = fmaf(alA, A[j].z, bs[j].z);
        o.w = fmaf(alA, A[j].w, bs[j].w);
        __builtin_nontemporal_store(o, &oa[j * 64 + lane]);
    }
#pragma unroll
    for (int j = 0; j < 4; ++j) {
        floatx4 o;
        o.x = fmaf(alB, B[j].x, bs[j].x);
        o.y = fmaf(alB, B[j].y, bs[j].y);
        o.z = fmaf(alB, B[j].z, bs[j].z);
        o.w = fmaf(alB, B[j].w, bs[j].w);
        __builtin_nontemporal_store(o, &ob[j * 64 + lane]);
    }
}

extern "C" void kernel_launch(void* const* d_in, const int* in_sizes, int n_in,
                              void* d_out, int out_size, void* d_ws, size_t ws_size,
                              hipStream_t stream) {
    const float* x0 = (const float*)d_in[0];
    const float* W  = (const float*)d_in[1];
    const float* b  = (const float*)d_in[2];
    float* out      = (float*)d_out;

    crossnet_kernel<<<NBLOCKS, THREADS, 0, stream>>>(x0, W, b, out);
}